// Round 1
// baseline (101.308 us; speedup 1.0000x reference)
//
#include <hip/hip_runtime.h>

// NNSubmulti additive-attention block, MI355X (gfx950).
// B=16, TK=TQ=128, E=256, H=100.
//
// Two kernels (was four):
// K1 prep:  blocks 0..255  : a[b,i,h] = (b1[h] + keys[b,i,:]·W1[h,:E]) * 2log2e
//                            c[b,j,h] = (queries[b,j,:]·W1[h,E:])      * 2log2e
//           via bf16 MFMA; X-rows and W1-half converted f32->bf16 inline.
//           blocks 256..319: convert Wlast f32 -> Wb bf16 [256][512].
// K2 attn:  per block = batch b x 4 key-rows. sim (exp2-form tanh) -> softmax
//           -> p·queries -> features (bf16, LDS) -> fused last GEMM (MFMA,
//           B-frags streamed from L2-resident Wb) -> relu -> out. No feat
//           round-trip, no separate last_gemm kernel.

namespace {
constexpr int B  = 16;
constexpr int TQ = 128;
constexpr int TK = 128;
constexpr int E  = 256;
constexpr int H  = 100;
constexpr int HP = 112;   // padded H: 4 quarters x 7 float4
constexpr int G  = 4;     // key-rows per attn block -> 512 blocks
constexpr float SCALE = 2.8853900817779268f;   // 2*log2(e)
}

typedef __attribute__((ext_vector_type(8))) short short8;   // 8 bf16 = 4 VGPRs
typedef __attribute__((ext_vector_type(4))) float f32x4;

__device__ __forceinline__ unsigned short f2bf(float f) {
  unsigned u = __builtin_bit_cast(unsigned, f);
  u = (u + 0x7FFFu + ((u >> 16) & 1u)) >> 16;   // round-to-nearest-even
  return (unsigned short)u;
}

// packed f32x2 -> bf16x2 (RTNE), one instruction
__device__ __forceinline__ unsigned cvt_pk(float lo, float hi) {
  unsigned r;
  asm("v_cvt_pk_bf16_f32 %0, %1, %2" : "=v"(r) : "v"(lo), "v"(hi));
  return r;
}

__device__ __forceinline__ uint4 cvt8(float4 v0, float4 v1) {
  return make_uint4(cvt_pk(v0.x, v0.y), cvt_pk(v0.z, v0.w),
                    cvt_pk(v1.x, v1.y), cvt_pk(v1.z, v1.w));
}

// ---------------------------------------------------------------- K1 ----
// Block = 16 X-rows x 112 h. A-operand = X rows (bf16), B-operand = W1 half
// ([N=h][K=e]). 7 N-tiles of 16, K = 256 (8 mfma steps). Conversion inline.
__global__ __launch_bounds__(256) void prep_mfma(
    const float* __restrict__ queries, const float* __restrict__ keys,
    const float* __restrict__ W1, const float* __restrict__ b1,
    const float* __restrict__ Wlast,
    float* __restrict__ A, float* __restrict__ C,
    unsigned short* __restrict__ Wb) {
  const int t = threadIdx.x;

  if (blockIdx.x >= 256) {          // ---- Wlast -> Wb bf16 (64 blocks) ----
    const int idx = ((blockIdx.x - 256) * 256 + t) * 8;   // 131072 floats
    float4 v0 = *(const float4*)(Wlast + idx);
    float4 v1 = *(const float4*)(Wlast + idx + 4);
    *(uint4*)(Wb + idx) = cvt8(v0, v1);
    return;
  }

  __shared__ short Bs[112 * 264];   // 59.1 KB (row stride 264 shorts: +8 pad)
  __shared__ short As[16 * 264];    //  8.4 KB
  const int m0 = blockIdx.x * 16;          // 256 blocks cover 4096 rows
  const bool isA = (m0 < B * TK);
  const int koff = isA ? 0 : 256;          // W1[:, :E] vs W1[:, E:]
  const float* Xsrc = isA ? keys + (size_t)m0 * E
                          : queries + (size_t)(m0 - B * TK) * E;
  float* dst = isA ? (A + (size_t)m0 * HP)
                   : (C + (size_t)(m0 - B * TK) * HP);

  #pragma unroll
  for (int i = 0; i < 14; ++i) {           // stage B: 112 x 256, convert f32->bf16
    const int idx = i * 256 + t;           // 3584 = 112 rows x 32 segs
    const int h = idx >> 5, seg = idx & 31;
    uint4 o;
    if (h < H) {
      const float* s = W1 + (size_t)h * 512 + koff + seg * 8;
      o = cvt8(*(const float4*)s, *(const float4*)(s + 4));
    } else {
      o = make_uint4(0u, 0u, 0u, 0u);      // zero-pad h >= 100
    }
    *(uint4*)(Bs + h * 264 + seg * 8) = o;
  }
  #pragma unroll
  for (int i = 0; i < 2; ++i) {            // stage A: 16 x 256, convert
    const int idx = i * 256 + t;
    const int r = idx >> 5, seg = idx & 31;
    const float* s = Xsrc + (size_t)r * E + seg * 8;
    *(uint4*)(As + r * 264 + seg * 8) = cvt8(*(const float4*)s,
                                             *(const float4*)(s + 4));
  }
  __syncthreads();

  const int wave = t >> 6, lane = t & 63;
  const int m = lane & 15, kq = lane >> 4;
  const int nt0 = wave, nt1 = wave + 4;    // tiles {w, w+4}; wave3 has 1 tile
  f32x4 acc0 = {0.f, 0.f, 0.f, 0.f}, acc1 = {0.f, 0.f, 0.f, 0.f};

  #pragma unroll
  for (int kc = 0; kc < 8; ++kc) {
    short8 a = *(const short8*)(As + m * 264 + kc * 32 + kq * 8);
    short8 bv0 = *(const short8*)(Bs + (nt0 * 16 + m) * 264 + kc * 32 + kq * 8);
    acc0 = __builtin_amdgcn_mfma_f32_16x16x32_bf16(a, bv0, acc0, 0, 0, 0);
    if (nt1 < 7) {
      short8 bv1 = *(const short8*)(Bs + (nt1 * 16 + m) * 264 + kc * 32 + kq * 8);
      acc1 = __builtin_amdgcn_mfma_f32_16x16x32_bf16(a, bv1, acc1, 0, 0, 0);
    }
  }

  // epilogue: D col=lane&15 -> h (N), row=(lane>>4)*4+reg -> X-row (M)
  // Prescale by 2*log2(e) so K2 can use exp2 directly: exp2(S*(a+c+b1)) = e^{2x}.
  const int rbase = (lane >> 4) * 4;
  {
    const int h = nt0 * 16 + m;
    const float bias = (isA && h < H) ? b1[h] : 0.0f;
    #pragma unroll
    for (int r = 0; r < 4; ++r)
      dst[(size_t)(rbase + r) * HP + h] = (acc0[r] + bias) * SCALE;
  }
  if (nt1 < 7) {
    const int h = nt1 * 16 + m;
    const float bias = (isA && h < H) ? b1[h] : 0.0f;
    #pragma unroll
    for (int r = 0; r < 4; ++r)
      dst[(size_t)(rbase + r) * HP + h] = (acc1[r] + bias) * SCALE;
  }
}

// ---------------------------------------------------------------- K2 ----
__global__ __launch_bounds__(512) void attn_core(
    const float* __restrict__ queries, const float* __restrict__ keys,
    const float* __restrict__ qmask, const float* __restrict__ kmask,
    const float* __restrict__ W2, const float* __restrict__ A,
    const float* __restrict__ C, const unsigned short* __restrict__ Wb,
    const float* __restrict__ blast, float* __restrict__ out) {
  __shared__ float a_s[G * HP];
  __shared__ float w2s[HP];
  __shared__ float qm[TQ];
  __shared__ float simP[G * 512];    // 8 KB: per-(g, q, j) partial sims
  __shared__ float pL[G * TQ];       // 2 KB: softmax probabilities
  __shared__ float red[8];
  __shared__ short feat_s[16 * 520]; // 16.6 KB; rows 0..3 valid, 4..15 garbage
                                     // (MFMA D-row r depends only on A-row r)

  const int t   = threadIdx.x;
  const int blk = blockIdx.x;        // 512 blocks
  const int b   = blk >> 5;          // 32 blocks per batch
  const int i0  = (blk & 31) * G;

  if (t < G * HP / 4)
    ((float4*)a_s)[t] = ((const float4*)(A + ((size_t)b * TK + i0) * HP))[t];
  if (t < HP) w2s[t] = (t < H) ? W2[t] : 0.0f;
  if (t < TQ) qm[t]  = qmask[b * TQ + t];
  __syncthreads();

  // ---- phase 1: sim partials, no barriers inside ----
  // A/C are prescaled by 2*log2(e): tanh(x) = 1 - 2*rcp(exp2(a+c) + 1)
  const int j = t & (TQ - 1);
  const int q = t >> 7;              // h-quarter 0..3
  float4 cr[7], wr[7];
  float wsum = 0.0f;
  {
    const float4* c4 = (const float4*)(C + ((size_t)b * TQ + j) * HP + q * 28);
    const float4* w4 = (const float4*)w2s + q * 7;
    #pragma unroll
    for (int k = 0; k < 7; ++k) {
      cr[k] = c4[k];                 // L2-resident, reused across 4 g
      wr[k] = w4[k];
      wsum += wr[k].x + wr[k].y + wr[k].z + wr[k].w;
    }
  }
  {
    const float4* a4p = (const float4*)a_s + q * 7;
    #pragma unroll
    for (int g = 0; g < G; ++g) {
      float s = 0.0f;                // s = sum_h w[h] * rcp(exp2(a+c)+1)
      #pragma unroll
      for (int k = 0; k < 7; ++k) {
        float4 a4 = a4p[g * (HP / 4) + k];   // wave-uniform broadcast
        float x0 = a4.x + cr[k].x, x1 = a4.y + cr[k].y;
        float x2 = a4.z + cr[k].z, x3 = a4.w + cr[k].w;
        s = fmaf(wr[k].x, __builtin_amdgcn_rcpf(__builtin_amdgcn_exp2f(x0) + 1.0f), s);
        s = fmaf(wr[k].y, __builtin_amdgcn_rcpf(__builtin_amdgcn_exp2f(x1) + 1.0f), s);
        s = fmaf(wr[k].z, __builtin_amdgcn_rcpf(__builtin_amdgcn_exp2f(x2) + 1.0f), s);
        s = fmaf(wr[k].w, __builtin_amdgcn_rcpf(__builtin_amdgcn_exp2f(x3) + 1.0f), s);
      }
      simP[g * 512 + t] = wsum - 2.0f * s;   // sum_h w*(1-2r) for this quarter
    }
  }
  __syncthreads();

  // ---- phase 2: softmax for all G rows in parallel ----
  {
    const int g2 = t >> 7, j2 = t & 127;
    const float* sp = simP + g2 * 512 + j2;
    float sv = sp[0] + sp[128] + sp[256] + sp[384];
    if (qm[j2] == 0.0f) sv = -4294967295.0f;   // -2^32+1
    float p = __expf(sv);                       // |sim| <= sum|W2| ~ 24: safe
    float s = p;
    #pragma unroll
    for (int off = 1; off < 64; off <<= 1) s += __shfl_xor(s, off, 64);
    if ((t & 63) == 0) red[t >> 6] = s;
    __syncthreads();
    pL[t] = p / (red[g2 * 2] + red[g2 * 2 + 1]);
  }
  __syncthreads();

  // ---- phase 3: keys_attn + features -> feat_s (bf16), 2 g per thread ----
  {
    const int e = t & 255, gh = t >> 8;
    float ka0 = 0.0f, ka1 = 0.0f;
    const float* qb = queries + (size_t)b * TQ * E + e;
    const float4* p4 = (const float4*)pL;
    for (int j4 = 0; j4 < TQ / 4; ++j4) {
      float4 p0 = p4[(gh * 2) * 32 + j4];      // broadcast
      float4 p1 = p4[(gh * 2 + 1) * 32 + j4];
      #pragma unroll
      for (int c = 0; c < 4; ++c) {
        float qv = qb[(size_t)(j4 * 4 + c) * E];   // coalesced
        ka0 = fmaf(((const float*)&p0)[c], qv, ka0);
        ka1 = fmaf(((const float*)&p1)[c], qv, ka1);
      }
    }
    #pragma unroll
    for (int gg = 0; gg < 2; ++gg) {
      const int g = gh * 2 + gg;
      const float ka = gg ? ka1 : ka0;
      const float kmv = kmask[b * TK + i0 + g];
      const float kav = ka * kmv;
      const float kv  = keys[((size_t)b * TK + i0 + g) * E + e];
      feat_s[g * 520 + e]     = (short)f2bf(kav * kv);   // feature_mul
      float d = kav - kv;
      feat_s[g * 520 + E + e] = (short)f2bf(d * d);      // feature_sub
    }
  }
  __syncthreads();

  // ---- phase 4: fused last GEMM ----
  // out[4, 256] = relu(feat[4, 512] @ Wlast^T + blast). 8 waves x 32 N-cols.
  // A-frag from feat_s (rows 4-15 garbage -> D rows 4-15 discarded);
  // B-frags streamed from L2-resident Wb (256 KB, shared by all blocks).
  {
    const int wave = t >> 6, lane = t & 63;
    const int nsub = wave * 32;
    const int m = lane & 15, kq = lane >> 4;
    f32x4 acc0 = {0.f, 0.f, 0.f, 0.f}, acc1 = {0.f, 0.f, 0.f, 0.f};
    const unsigned short* wb0 = Wb + (size_t)(nsub + m) * 512 + kq * 8;
    const unsigned short* wb1 = wb0 + (size_t)16 * 512;
    const short* ap = feat_s + m * 520 + kq * 8;
    #pragma unroll
    for (int ks = 0; ks < 16; ++ks) {          // K = 512 in steps of 32
      short8 a  = *(const short8*)(ap + ks * 32);
      short8 b0 = *(const short8*)(wb0 + ks * 32);
      acc0 = __builtin_amdgcn_mfma_f32_16x16x32_bf16(a, b0, acc0, 0, 0, 0);
      short8 b1v = *(const short8*)(wb1 + ks * 32);
      acc1 = __builtin_amdgcn_mfma_f32_16x16x32_bf16(a, b1v, acc1, 0, 0, 0);
    }
    // D: row = (lane>>4)*4 + r, col = lane&15. Valid rows 0..3 -> lanes 0..15.
    if (lane < 16) {
      const size_t row0 = (size_t)(b * TK + i0) * 256;
      const int e0 = nsub + lane, e1 = nsub + 16 + lane;
      const float bl0 = blast[e0], bl1 = blast[e1];
      #pragma unroll
      for (int r = 0; r < 4; ++r) {
        out[row0 + (size_t)r * 256 + e0] = fmaxf(acc0[r] + bl0, 0.0f);
        out[row0 + (size_t)r * 256 + e1] = fmaxf(acc1[r] + bl1, 0.0f);
      }
    }
  }
}

// ------------------------------------------------------------- launch ----
extern "C" void kernel_launch(void* const* d_in, const int* in_sizes, int n_in,
                              void* d_out, int out_size, void* d_ws, size_t ws_size,
                              hipStream_t stream) {
  (void)in_sizes; (void)n_in; (void)out_size; (void)ws_size;
  const float* queries = (const float*)d_in[0];
  const float* keys    = (const float*)d_in[1];
  const float* qmask   = (const float*)d_in[2];
  const float* kmask   = (const float*)d_in[3];
  const float* W1      = (const float*)d_in[4];
  const float* b1      = (const float*)d_in[5];
  const float* W2      = (const float*)d_in[6];
  const float* Wlast   = (const float*)d_in[7];
  const float* blast   = (const float*)d_in[8];
  float* out = (float*)d_out;

  float* A = (float*)d_ws;                               // [2048][112] f32
  float* C = A + (size_t)B * TK * HP;                    // [2048][112] f32
  unsigned short* Wb = (unsigned short*)(C + (size_t)B * TQ * HP); // [256][512]
  // total ws ~ 2.1 MiB

  prep_mfma<<<dim3(320), dim3(256), 0, stream>>>(
      queries, keys, W1, b1, Wlast, A, C, Wb);
  attn_core<<<dim3(B * (TK / G)), dim3(512), 0, stream>>>(
      queries, keys, qmask, kmask, W2, A, C, Wb, blast, out);
}